// Round 2
// baseline (1079.546 us; speedup 1.0000x reference)
//
#include <hip/hip_runtime.h>

#define NB 4
#define NS 1024
#define NH 256
#define NR 65536
#define NF 768
#define NK 512

typedef __attribute__((ext_vector_type(8))) short bf16x8;
typedef __attribute__((ext_vector_type(4))) float f32x4;

static __device__ __forceinline__ unsigned short f2bf(float f) {
  unsigned int u = __builtin_bit_cast(unsigned int, f);
  u += 0x7FFFu + ((u >> 16) & 1u);   // RTNE
  return (unsigned short)(u >> 16);
}

// rel_ids may arrive as int32 or int64. Values are in [0,1024), so if int64,
// every odd int32 word (the high half) is zero. Sample 8192 odd words.
__global__ void detect_idw(const int* __restrict__ ids, int* __restrict__ flag) {
  __shared__ int anynz;
  if (threadIdx.x == 0) anynz = 0;
  __syncthreads();
  int acc = 0;
  for (int i = threadIdx.x; i < 8192; i += 256) acc |= ids[2 * i + 1];
  if (acc != 0) atomicOr(&anynz, 1);
  __syncthreads();
  if (threadIdx.x == 0) flag[0] = (anynz == 0) ? 1 : 0;  // 1 => int64 layout
}

// W1 (512x768) f32 -> W1T (768x512) bf16
__global__ void prep_w1(const float* __restrict__ w1, unsigned short* __restrict__ w1t) {
  int i = blockIdx.x * 256 + threadIdx.x;   // 768*512 = 393216
  int n = i >> 9, k = i & 511;
  w1t[i] = f2bf(w1[k * NF + n]);
}

// W2 (768x256) f32 -> W2T (256x768) bf16
__global__ void prep_w2(const float* __restrict__ w2, unsigned short* __restrict__ w2t) {
  int i = blockIdx.x * 256 + threadIdx.x;   // 256*768 = 196608
  int n = i / NF, k = i - n * NF;
  w2t[i] = f2bf(w2[k * NH + n]);
}

// Fused: gather -> GEMM1(relu,+b1) -> GEMM2(+b2).
// 64 rows per block, 8 waves (512 thr) in a 2M x 4N wave grid.
// LDS 80 KB -> 2 blocks/CU -> 16 waves/CU (4/SIMD).
__global__ __launch_bounds__(512, 4)
void fused_relffn(const float* __restrict__ span, const int* __restrict__ ids,
                  const float* __restrict__ b1, const float* __restrict__ b2,
                  const unsigned short* __restrict__ w1t,
                  const unsigned short* __restrict__ w2t,
                  const int* __restrict__ flagp, float* __restrict__ out) {
  __shared__ __align__(16) unsigned short As[64 * 512];  // 64 KB, swizzled
  __shared__ __align__(16) unsigned short Hs[64 * 128];  // 16 KB, swizzled

  const int tid = threadIdx.x;
  const int blk = blockIdx.x;
  const int bb = blk >> 10;              // batch
  const int r0 = (blk & 1023) << 6;      // first relation row
  const int lane = tid & 63;
  const int w = tid >> 6;                // wave 0..7
  const int wm = w & 1;                  // row-group 0..1 (32 rows each)
  const int wn = w >> 1;                 // col-group 0..3
  const int l15 = lane & 15;
  const int lq = lane >> 4;              // 0..3
  const int is64 = flagp[0];

  // ---- gather A tile: 64 rows x 512 (head|tail), f32 -> bf16, swizzled ----
  {
    const long pair0 = ((long)bb * NR + r0) * 2;
#pragma unroll
    for (int j = 0; j < 8; ++j) {
      int g = tid + j * 512;             // 0..4095 chunk id
      int row = g >> 6;                  // 0..63
      int kc = g & 63;                   // 8-float chunk within row
      long pidx = pair0 + row * 2 + (kc >> 5);     // head / tail id slot
      int id = is64 ? ids[pidx * 2] : ids[pidx];
      const float* src = span + ((size_t)bb * NS + id) * NH + (kc & 31) * 8;
      float4 v0 = *(const float4*)src;
      float4 v1 = *(const float4*)(src + 4);
      uint4 pk;
      pk.x = f2bf(v0.x) | ((unsigned)f2bf(v0.y) << 16);
      pk.y = f2bf(v0.z) | ((unsigned)f2bf(v0.w) << 16);
      pk.z = f2bf(v1.x) | ((unsigned)f2bf(v1.y) << 16);
      pk.w = f2bf(v1.z) | ((unsigned)f2bf(v1.w) << 16);
      int idx = row * 512 + ((kc * 8) ^ ((row & 7) << 3));  // XOR swizzle (16B units)
      *(uint4*)&As[idx] = pk;
    }
  }
  __syncthreads();

  f32x4 acc2[2][4];
#pragma unroll
  for (int mi = 0; mi < 2; ++mi)
#pragma unroll
    for (int nj = 0; nj < 4; ++nj) {
      f32x4 z = {0.f, 0.f, 0.f, 0.f};
      acc2[mi][nj] = z;
    }

  for (int c = 0; c < 6; ++c) {
    // ---- GEMM1: wave computes rows [wm*32,+32) x chunk cols [wn*32,+32)
    // swapped operands: D[n][m] = mfma(A=W1T frag, B=As frag) ----
    f32x4 acc1[2][2];
#pragma unroll
    for (int mi = 0; mi < 2; ++mi)
#pragma unroll
      for (int ni = 0; ni < 2; ++ni) {
        f32x4 z = {0.f, 0.f, 0.f, 0.f};
        acc1[mi][ni] = z;
      }
    const unsigned short* w1p = w1t + ((c * 128 + wn * 32 + l15) * NK + lq * 8);
#pragma unroll 4
    for (int kk = 0; kk < 16; ++kk) {
      bf16x8 wf0 = *(const bf16x8*)(w1p + kk * 32);
      bf16x8 wf1 = *(const bf16x8*)(w1p + 16 * NK + kk * 32);
      bf16x8 af[2];
#pragma unroll
      for (int mi = 0; mi < 2; ++mi) {
        int row = wm * 32 + mi * 16 + l15;
        int kidx = kk * 32 + lq * 8;
        af[mi] = *(const bf16x8*)&As[row * 512 + (kidx ^ ((row & 7) << 3))];
      }
#pragma unroll
      for (int mi = 0; mi < 2; ++mi) {
        acc1[mi][0] = __builtin_amdgcn_mfma_f32_16x16x32_bf16(wf0, af[mi], acc1[mi][0], 0, 0, 0);
        acc1[mi][1] = __builtin_amdgcn_mfma_f32_16x16x32_bf16(wf1, af[mi], acc1[mi][1], 0, 0, 0);
      }
    }
    __syncthreads();   // prior chunk's Hs reads done before overwrite
    // bias + relu + bf16 pack; lane holds 4 consecutive n for fixed m
#pragma unroll
    for (int ni = 0; ni < 2; ++ni) {
      int n0 = c * 128 + wn * 32 + ni * 16 + lq * 4;
      float4 bv = *(const float4*)(b1 + n0);
#pragma unroll
      for (int mi = 0; mi < 2; ++mi) {
        f32x4 a = acc1[mi][ni];
        float x0 = fmaxf(a[0] + bv.x, 0.0f);
        float x1 = fmaxf(a[1] + bv.y, 0.0f);
        float x2 = fmaxf(a[2] + bv.z, 0.0f);
        float x3 = fmaxf(a[3] + bv.w, 0.0f);
        int m = wm * 32 + mi * 16 + l15;
        int nl0 = wn * 32 + ni * 16 + lq * 4;
        uint2 pk;
        pk.x = f2bf(x0) | ((unsigned)f2bf(x1) << 16);
        pk.y = f2bf(x2) | ((unsigned)f2bf(x3) << 16);
        *(uint2*)&Hs[m * 128 + (nl0 ^ ((m & 7) << 3))] = pk;
      }
    }
    __syncthreads();
    // ---- GEMM2 partial: rows [wm*32,+32) x out cols [wn*64,+64) ----
    const unsigned short* w2p = w2t + ((wn * 64 + l15) * NF + c * 128 + lq * 8);
#pragma unroll
    for (int kq = 0; kq < 4; ++kq) {
      bf16x8 vf[4];
#pragma unroll
      for (int nj = 0; nj < 4; ++nj)
        vf[nj] = *(const bf16x8*)(w2p + nj * 16 * NF + kq * 32);
      bf16x8 hf[2];
#pragma unroll
      for (int mi = 0; mi < 2; ++mi) {
        int row = wm * 32 + mi * 16 + l15;
        int kidx = kq * 32 + lq * 8;
        hf[mi] = *(const bf16x8*)&Hs[row * 128 + (kidx ^ ((row & 7) << 3))];
      }
#pragma unroll
      for (int mi = 0; mi < 2; ++mi)
#pragma unroll
        for (int nj = 0; nj < 4; ++nj)
          acc2[mi][nj] = __builtin_amdgcn_mfma_f32_16x16x32_bf16(vf[nj], hf[mi], acc2[mi][nj], 0, 0, 0);
    }
  }

  // ---- epilogue: +b2, float4 stores (lane owns 4 consecutive nout) ----
#pragma unroll
  for (int nj = 0; nj < 4; ++nj) {
    int n0 = wn * 64 + nj * 16 + lq * 4;
    float4 bv = *(const float4*)(b2 + n0);
#pragma unroll
    for (int mi = 0; mi < 2; ++mi) {
      int m = wm * 32 + mi * 16 + l15;
      f32x4 a = acc2[mi][nj];
      float4 o;
      o.x = a[0] + bv.x; o.y = a[1] + bv.y; o.z = a[2] + bv.z; o.w = a[3] + bv.w;
      *(float4*)(out + ((size_t)bb * NR + r0 + m) * NH + n0) = o;
    }
  }
}

extern "C" void kernel_launch(void* const* d_in, const int* in_sizes, int n_in,
                              void* d_out, int out_size, void* d_ws, size_t ws_size,
                              hipStream_t stream) {
  const float* span = (const float*)d_in[0];
  const int* ids = (const int*)d_in[1];
  const float* W1 = (const float*)d_in[2];
  const float* b1 = (const float*)d_in[3];
  const float* W2 = (const float*)d_in[4];
  const float* b2 = (const float*)d_in[5];
  float* out = (float*)d_out;

  char* ws = (char*)d_ws;
  int* flag = (int*)ws;
  unsigned short* w1t = (unsigned short*)(ws + 64);                    // 768x512 bf16
  unsigned short* w2t = (unsigned short*)(ws + 64 + NF * NK * 2);      // 256x768 bf16

  detect_idw<<<1, 256, 0, stream>>>(ids, flag);
  prep_w1<<<(NF * NK) / 256, 256, 0, stream>>>(W1, w1t);
  prep_w2<<<(NH * NF) / 256, 256, 0, stream>>>(W2, w2t);
  fused_relffn<<<4096, 512, 0, stream>>>(span, ids, b1, b2, w1t, w2t, flag, out);
}

// Round 3
// 583.992 us; speedup vs baseline: 1.8486x; 1.8486x over previous
//
#include <hip/hip_runtime.h>

#define NB 4
#define NS 1024
#define NH 256
#define NR 65536
#define NF 768
#define NK 512

typedef __attribute__((ext_vector_type(8))) short bf16x8;
typedef __attribute__((ext_vector_type(4))) float f32x4;

static __device__ __forceinline__ unsigned short f2bf(float f) {
  unsigned int u = __builtin_bit_cast(unsigned int, f);
  u += 0x7FFFu + ((u >> 16) & 1u);   // RTNE
  return (unsigned short)(u >> 16);
}

// Raw barrier: lgkmcnt(0) only -- does NOT drain vmcnt, so prefetched global
// weight loads stay in flight across the Hs barriers (T3/T4 mechanism).
#define BARRIER()                                            \
  do {                                                       \
    asm volatile("s_waitcnt lgkmcnt(0)" ::: "memory");       \
    __builtin_amdgcn_s_barrier();                            \
    asm volatile("" ::: "memory");                           \
  } while (0)

// rel_ids may arrive as int32 or int64. Values are in [0,1024), so if int64,
// every odd int32 word (the high half) is zero. Sample 8192 odd words.
__global__ void detect_idw(const int* __restrict__ ids, int* __restrict__ flag) {
  __shared__ int anynz;
  if (threadIdx.x == 0) anynz = 0;
  __syncthreads();
  int acc = 0;
  for (int i = threadIdx.x; i < 8192; i += 256) acc |= ids[2 * i + 1];
  if (acc != 0) atomicOr(&anynz, 1);
  __syncthreads();
  if (threadIdx.x == 0) flag[0] = (anynz == 0) ? 1 : 0;  // 1 => int64 layout
}

// W1 (512x768) f32 -> W1T (768x512) bf16
__global__ void prep_w1(const float* __restrict__ w1, unsigned short* __restrict__ w1t) {
  int i = blockIdx.x * 256 + threadIdx.x;   // 768*512 = 393216
  int n = i >> 9, k = i & 511;
  w1t[i] = f2bf(w1[k * NF + n]);
}

// W2 (768x256) f32 -> W2T (256x768) bf16
__global__ void prep_w2(const float* __restrict__ w2, unsigned short* __restrict__ w2t) {
  int i = blockIdx.x * 256 + threadIdx.x;   // 256*768 = 196608
  int n = i / NF, k = i - n * NF;
  w2t[i] = f2bf(w2[k * NH + n]);
}

// Fused: gather -> GEMM1(relu,+b1) -> GEMM2(+b2), 64 rows per block, 4 waves.
// R1 geometry + 4-deep W1-fragment prefetch + vmcnt-preserving barriers.
__global__ __launch_bounds__(256, 2)
void fused_relffn(const float* __restrict__ span, const int* __restrict__ ids,
                  const float* __restrict__ b1, const float* __restrict__ b2,
                  const unsigned short* __restrict__ w1t,
                  const unsigned short* __restrict__ w2t,
                  const int* __restrict__ flagp, float* __restrict__ out) {
  __shared__ __align__(16) unsigned short As[64 * 512];  // 64 KB, swizzled
  __shared__ __align__(16) unsigned short Hs[64 * 128];  // 16 KB, swizzled

  const int tid = threadIdx.x;
  const int blk = blockIdx.x;
  const int bb = blk >> 10;              // batch
  const int r0 = (blk & 1023) << 6;      // first relation row
  const int lane = tid & 63;
  const int w = tid >> 6;                // wave 0..3
  const int l15 = lane & 15;
  const int lq = lane >> 4;              // 0..3
  const int is64 = flagp[0];

  // W1T fragment base for this wave (add c*128*NK per chunk)
  const unsigned short* w1base = w1t + ((w * 32 + l15) * NK + lq * 8);

  // ---- prefetch chunk-0 GEMM1 prologue (kk=0..3) BEFORE the gather barrier ----
  bf16x8 wf[4][2];
#pragma unroll
  for (int s = 0; s < 4; ++s) {
    wf[s][0] = *(const bf16x8*)(w1base + s * 32);
    wf[s][1] = *(const bf16x8*)(w1base + 16 * NK + s * 32);
  }

  // ---- gather A tile: 64 rows x 512 (head|tail), f32 -> bf16, swizzled ----
  {
    const long pair0 = ((long)bb * NR + r0) * 2;
#pragma unroll
    for (int j = 0; j < 16; ++j) {
      int g = tid + j * 256;             // 0..4095 chunk id
      int row = g >> 6;                  // 0..63
      int kc = g & 63;                   // 8-float chunk within row
      long pidx = pair0 + row * 2 + (kc >> 5);     // head / tail id slot
      int id = is64 ? ids[pidx * 2] : ids[pidx];
      const float* src = span + ((size_t)bb * NS + id) * NH + (kc & 31) * 8;
      float4 v0 = *(const float4*)src;
      float4 v1 = *(const float4*)(src + 4);
      uint4 pk;
      pk.x = f2bf(v0.x) | ((unsigned)f2bf(v0.y) << 16);
      pk.y = f2bf(v0.z) | ((unsigned)f2bf(v0.w) << 16);
      pk.z = f2bf(v1.x) | ((unsigned)f2bf(v1.y) << 16);
      pk.w = f2bf(v1.z) | ((unsigned)f2bf(v1.w) << 16);
      int idx = row * 512 + ((kc * 8) ^ ((row & 7) << 3));  // XOR swizzle (16B units)
      *(uint4*)&As[idx] = pk;
    }
  }
  BARRIER();

  f32x4 acc2[4][4];
#pragma unroll
  for (int mi = 0; mi < 4; ++mi)
#pragma unroll
    for (int nj = 0; nj < 4; ++nj) {
      f32x4 z = {0.f, 0.f, 0.f, 0.f};
      acc2[mi][nj] = z;
    }

  for (int c = 0; c < 6; ++c) {
    const unsigned short* w1p = w1base + c * 128 * NK;
    // ---- GEMM1: h-slice (64 x 128), 4-deep rotating W-fragment prefetch ----
    f32x4 acc1[4][2];
#pragma unroll
    for (int mi = 0; mi < 4; ++mi)
#pragma unroll
      for (int ni = 0; ni < 2; ++ni) {
        f32x4 z = {0.f, 0.f, 0.f, 0.f};
        acc1[mi][ni] = z;
      }
#pragma unroll
    for (int kk = 0; kk < 16; ++kk) {
      const int s = kk & 3;
      bf16x8 cw0 = wf[s][0];
      bf16x8 cw1 = wf[s][1];
      if (kk < 12) {   // refill slot with kk+4
        wf[s][0] = *(const bf16x8*)(w1p + (kk + 4) * 32);
        wf[s][1] = *(const bf16x8*)(w1p + 16 * NK + (kk + 4) * 32);
      }
      bf16x8 af[4];
#pragma unroll
      for (int mi = 0; mi < 4; ++mi) {
        int row = mi * 16 + l15;
        int kidx = kk * 32 + lq * 8;
        af[mi] = *(const bf16x8*)&As[row * 512 + (kidx ^ ((row & 7) << 3))];
      }
#pragma unroll
      for (int mi = 0; mi < 4; ++mi) {
        acc1[mi][0] = __builtin_amdgcn_mfma_f32_16x16x32_bf16(cw0, af[mi], acc1[mi][0], 0, 0, 0);
        acc1[mi][1] = __builtin_amdgcn_mfma_f32_16x16x32_bf16(cw1, af[mi], acc1[mi][1], 0, 0, 0);
      }
    }
    // ---- prefetch next chunk's GEMM1 prologue; survives the barriers below ----
    if (c < 5) {
      const unsigned short* np = w1base + (c + 1) * 128 * NK;
#pragma unroll
      for (int s = 0; s < 4; ++s) {
        wf[s][0] = *(const bf16x8*)(np + s * 32);
        wf[s][1] = *(const bf16x8*)(np + 16 * NK + s * 32);
      }
    }
    BARRIER();   // prior chunk's Hs reads done before overwrite
    // bias + relu + bf16 pack; lane holds 4 consecutive n for fixed m
#pragma unroll
    for (int ni = 0; ni < 2; ++ni) {
      int n0 = c * 128 + w * 32 + ni * 16 + lq * 4;
      float4 bv = *(const float4*)(b1 + n0);
#pragma unroll
      for (int mi = 0; mi < 4; ++mi) {
        f32x4 a = acc1[mi][ni];
        float x0 = fmaxf(a[0] + bv.x, 0.0f);
        float x1 = fmaxf(a[1] + bv.y, 0.0f);
        float x2 = fmaxf(a[2] + bv.z, 0.0f);
        float x3 = fmaxf(a[3] + bv.w, 0.0f);
        int m = mi * 16 + l15;
        int nl0 = w * 32 + ni * 16 + lq * 4;
        uint2 pk;
        pk.x = f2bf(x0) | ((unsigned)f2bf(x1) << 16);
        pk.y = f2bf(x2) | ((unsigned)f2bf(x3) << 16);
        *(uint2*)&Hs[m * 128 + (nl0 ^ ((m & 7) << 3))] = pk;
      }
    }
    BARRIER();
    // ---- GEMM2 partial: acc2 += W2[c*128:+128, :] (as W2T frags) @ h-slice ----
    const unsigned short* w2p = w2t + ((w * 64 + l15) * NF + c * 128 + lq * 8);
#pragma unroll
    for (int kq = 0; kq < 4; ++kq) {
      bf16x8 vf[4];
#pragma unroll
      for (int nj = 0; nj < 4; ++nj)
        vf[nj] = *(const bf16x8*)(w2p + nj * 16 * NF + kq * 32);
      bf16x8 hf[4];
#pragma unroll
      for (int mi = 0; mi < 4; ++mi) {
        int row = mi * 16 + l15;
        int kidx = kq * 32 + lq * 8;
        hf[mi] = *(const bf16x8*)&Hs[row * 128 + (kidx ^ ((row & 7) << 3))];
      }
#pragma unroll
      for (int mi = 0; mi < 4; ++mi)
#pragma unroll
        for (int nj = 0; nj < 4; ++nj)
          acc2[mi][nj] = __builtin_amdgcn_mfma_f32_16x16x32_bf16(vf[nj], hf[mi], acc2[mi][nj], 0, 0, 0);
    }
  }

  // ---- epilogue: +b2, float4 stores (lane owns 4 consecutive nout) ----
#pragma unroll
  for (int nj = 0; nj < 4; ++nj) {
    int n0 = w * 64 + nj * 16 + lq * 4;
    float4 bv = *(const float4*)(b2 + n0);
#pragma unroll
    for (int mi = 0; mi < 4; ++mi) {
      int m = mi * 16 + l15;
      f32x4 a = acc2[mi][nj];
      float4 o;
      o.x = a[0] + bv.x; o.y = a[1] + bv.y; o.z = a[2] + bv.z; o.w = a[3] + bv.w;
      *(float4*)(out + ((size_t)bb * NR + r0 + m) * NH + n0) = o;
    }
  }
}

extern "C" void kernel_launch(void* const* d_in, const int* in_sizes, int n_in,
                              void* d_out, int out_size, void* d_ws, size_t ws_size,
                              hipStream_t stream) {
  const float* span = (const float*)d_in[0];
  const int* ids = (const int*)d_in[1];
  const float* W1 = (const float*)d_in[2];
  const float* b1 = (const float*)d_in[3];
  const float* W2 = (const float*)d_in[4];
  const float* b2 = (const float*)d_in[5];
  float* out = (float*)d_out;

  char* ws = (char*)d_ws;
  int* flag = (int*)ws;
  unsigned short* w1t = (unsigned short*)(ws + 64);                    // 768x512 bf16
  unsigned short* w2t = (unsigned short*)(ws + 64 + NF * NK * 2);      // 256x768 bf16

  detect_idw<<<1, 256, 0, stream>>>(ids, flag);
  prep_w1<<<(NF * NK) / 256, 256, 0, stream>>>(W1, w1t);
  prep_w2<<<(NH * NF) / 256, 256, 0, stream>>>(W2, w2t);
  fused_relffn<<<4096, 256, 0, stream>>>(span, ids, b1, b2, w1t, w2t, flag, out);
}

// Round 4
// 347.212 us; speedup vs baseline: 3.1092x; 1.6819x over previous
//
#include <hip/hip_runtime.h>

#define NB 4
#define NS 1024
#define NH 256
#define NR 65536
#define NF 768
#define NK 512

typedef __attribute__((ext_vector_type(8))) short bf16x8;
typedef __attribute__((ext_vector_type(4))) float f32x4;

static __device__ __forceinline__ unsigned short f2bf(float f) {
  unsigned int u = __builtin_bit_cast(unsigned int, f);
  u += 0x7FFFu + ((u >> 16) & 1u);   // RTNE
  return (unsigned short)(u >> 16);
}

// Raw barrier: lgkmcnt(0) only -- does NOT drain vmcnt, so prefetched global
// weight loads stay in flight across the Hs barriers.
#define BARRIER()                                            \
  do {                                                       \
    asm volatile("s_waitcnt lgkmcnt(0)" ::: "memory");       \
    __builtin_amdgcn_s_barrier();                            \
    asm volatile("" ::: "memory");                           \
  } while (0)

// rel_ids may arrive as int32 or int64. Values are in [0,1024), so if int64,
// every odd int32 word (the high half) is zero. Sample 8192 odd words.
__global__ void detect_idw(const int* __restrict__ ids, int* __restrict__ flag) {
  __shared__ int anynz;
  if (threadIdx.x == 0) anynz = 0;
  __syncthreads();
  int acc = 0;
  for (int i = threadIdx.x; i < 8192; i += 256) acc |= ids[2 * i + 1];
  if (acc != 0) atomicOr(&anynz, 1);
  __syncthreads();
  if (threadIdx.x == 0) flag[0] = (anynz == 0) ? 1 : 0;  // 1 => int64 layout
}

// W1 (512x768 f32, k-major rows) -> W1F: MFMA-fragment-packed bf16.
// 16B unit u = (((c*4 + w)*2 + half)*16 + kk)*64 + lane holds
// W1col[row = c*128 + w*32 + half*16 + (lane&15)][k = kk*32 + (lane>>4)*8 +0..7]
// so each fused-kernel weight fetch is one contiguous 1KB wave load.
__global__ void prep_w1(const float* __restrict__ w1, unsigned short* __restrict__ w1f) {
  int t = blockIdx.x * 256 + threadIdx.x;   // 49152 units
  int l = t & 63;
  int kk = (t >> 6) & 15;
  int half = (t >> 10) & 1;
  int w = (t >> 11) & 3;
  int c = t >> 13;                          // 0..5
  int row = c * 128 + w * 32 + half * 16 + (l & 15);   // n index in [0,768)
  int k0 = kk * 32 + (l >> 4) * 8;                     // k index in [0,512)
  uint4 pk;
  unsigned short v[8];
#pragma unroll
  for (int j = 0; j < 8; ++j) v[j] = f2bf(w1[(size_t)(k0 + j) * NF + row]);
  pk.x = v[0] | ((unsigned)v[1] << 16);
  pk.y = v[2] | ((unsigned)v[3] << 16);
  pk.z = v[4] | ((unsigned)v[5] << 16);
  pk.w = v[6] | ((unsigned)v[7] << 16);
  *(uint4*)(w1f + (size_t)t * 8) = pk;
}

// W2 (768x256 f32) -> W2F fragment-packed bf16.
// unit u = (((w*4 + nj)*6 + c)*4 + kq)*64 + lane holds
// W2col[row = w*64 + nj*16 + (lane&15)][k = c*128 + kq*32 + (lane>>4)*8 +0..7]
__global__ void prep_w2(const float* __restrict__ w2, unsigned short* __restrict__ w2f) {
  int t = blockIdx.x * 256 + threadIdx.x;   // 24576 units
  int l = t & 63;
  int kq = (t >> 6) & 3;
  int rest = t >> 8;                        // (w*4+nj)*6 + c
  int c = rest % 6;
  int wn = rest / 6;                        // w*4 + nj
  int nj = wn & 3;
  int w = wn >> 2;
  int row = w * 64 + nj * 16 + (l & 15);    // n index in [0,256)
  int k = c * 128 + kq * 32 + (l >> 4) * 8; // k index in [0,768)
  uint4 pk;
  unsigned short v[8];
#pragma unroll
  for (int j = 0; j < 8; ++j) v[j] = f2bf(w2[(size_t)(k + j) * NH + row]);
  pk.x = v[0] | ((unsigned)v[1] << 16);
  pk.y = v[2] | ((unsigned)v[3] << 16);
  pk.z = v[4] | ((unsigned)v[5] << 16);
  pk.w = v[6] | ((unsigned)v[7] << 16);
  *(uint4*)(w2f + (size_t)t * 8) = pk;
}

// Fused: gather -> GEMM1(relu,+b1) -> GEMM2(+b2), 64 rows per block, 4 waves.
// R3 geometry with fragment-packed (fully coalesced) weight loads.
__global__ __launch_bounds__(256, 2)
void fused_relffn(const float* __restrict__ span, const int* __restrict__ ids,
                  const float* __restrict__ b1, const float* __restrict__ b2,
                  const unsigned short* __restrict__ w1f,
                  const unsigned short* __restrict__ w2f,
                  const int* __restrict__ flagp, float* __restrict__ out) {
  __shared__ __align__(16) unsigned short As[64 * 512];  // 64 KB, swizzled
  __shared__ __align__(16) unsigned short Hs[64 * 128];  // 16 KB, swizzled

  const int tid = threadIdx.x;
  const int blk = blockIdx.x;
  const int bb = blk >> 10;              // batch
  const int r0 = (blk & 1023) << 6;      // first relation row
  const int lane = tid & 63;
  const int w = tid >> 6;                // wave 0..3
  const int l15 = lane & 15;
  const int lq = lane >> 4;              // 0..3
  const int is64 = flagp[0];

  // Packed W1 base for this wave: + c*65536 per chunk; wf0 at +kk*512,
  // wf1 (half=1) at +8192+kk*512. All lane-contiguous.
  const unsigned short* w1base = w1f + w * 16384 + lane * 8;
  // Packed W2 base: + nj*12288 + c*2048 + kq*512.
  const unsigned short* w2base = w2f + w * 49152 + lane * 8;

  // ---- prefetch chunk-0 GEMM1 prologue (kk=0..3) BEFORE the gather barrier ----
  bf16x8 wf[4][2];
#pragma unroll
  for (int s = 0; s < 4; ++s) {
    wf[s][0] = *(const bf16x8*)(w1base + s * 512);
    wf[s][1] = *(const bf16x8*)(w1base + 8192 + s * 512);
  }

  // ---- gather A tile: 64 rows x 512 (head|tail), f32 -> bf16, swizzled ----
  {
    const long pair0 = ((long)bb * NR + r0) * 2;
#pragma unroll
    for (int j = 0; j < 16; ++j) {
      int g = tid + j * 256;             // 0..4095 chunk id
      int row = g >> 6;                  // 0..63
      int kc = g & 63;                   // 8-float chunk within row
      long pidx = pair0 + row * 2 + (kc >> 5);     // head / tail id slot
      int id = is64 ? ids[pidx * 2] : ids[pidx];
      const float* src = span + ((size_t)bb * NS + id) * NH + (kc & 31) * 8;
      float4 v0 = *(const float4*)src;
      float4 v1 = *(const float4*)(src + 4);
      uint4 pk;
      pk.x = f2bf(v0.x) | ((unsigned)f2bf(v0.y) << 16);
      pk.y = f2bf(v0.z) | ((unsigned)f2bf(v0.w) << 16);
      pk.z = f2bf(v1.x) | ((unsigned)f2bf(v1.y) << 16);
      pk.w = f2bf(v1.z) | ((unsigned)f2bf(v1.w) << 16);
      int idx = row * 512 + ((kc * 8) ^ ((row & 7) << 3));  // XOR swizzle (16B units)
      *(uint4*)&As[idx] = pk;
    }
  }
  BARRIER();

  f32x4 acc2[4][4];
#pragma unroll
  for (int mi = 0; mi < 4; ++mi)
#pragma unroll
    for (int nj = 0; nj < 4; ++nj) {
      f32x4 z = {0.f, 0.f, 0.f, 0.f};
      acc2[mi][nj] = z;
    }

  for (int c = 0; c < 6; ++c) {
    const unsigned short* w1p = w1base + c * 65536;
    // ---- GEMM1: h-slice (64 x 128), 4-deep rotating W-fragment prefetch ----
    f32x4 acc1[4][2];
#pragma unroll
    for (int mi = 0; mi < 4; ++mi)
#pragma unroll
      for (int ni = 0; ni < 2; ++ni) {
        f32x4 z = {0.f, 0.f, 0.f, 0.f};
        acc1[mi][ni] = z;
      }
#pragma unroll
    for (int kk = 0; kk < 16; ++kk) {
      const int s = kk & 3;
      bf16x8 cw0 = wf[s][0];
      bf16x8 cw1 = wf[s][1];
      if (kk < 12) {   // refill slot with kk+4
        wf[s][0] = *(const bf16x8*)(w1p + (kk + 4) * 512);
        wf[s][1] = *(const bf16x8*)(w1p + 8192 + (kk + 4) * 512);
      }
      bf16x8 af[4];
#pragma unroll
      for (int mi = 0; mi < 4; ++mi) {
        int row = mi * 16 + l15;
        int kidx = kk * 32 + lq * 8;
        af[mi] = *(const bf16x8*)&As[row * 512 + (kidx ^ ((row & 7) << 3))];
      }
#pragma unroll
      for (int mi = 0; mi < 4; ++mi) {
        acc1[mi][0] = __builtin_amdgcn_mfma_f32_16x16x32_bf16(cw0, af[mi], acc1[mi][0], 0, 0, 0);
        acc1[mi][1] = __builtin_amdgcn_mfma_f32_16x16x32_bf16(cw1, af[mi], acc1[mi][1], 0, 0, 0);
      }
    }
    // ---- prefetch next chunk's GEMM1 prologue; survives the barriers below ----
    if (c < 5) {
      const unsigned short* np = w1base + (c + 1) * 65536;
#pragma unroll
      for (int s = 0; s < 4; ++s) {
        wf[s][0] = *(const bf16x8*)(np + s * 512);
        wf[s][1] = *(const bf16x8*)(np + 8192 + s * 512);
      }
    }
    BARRIER();   // prior chunk's Hs reads done before overwrite
    // bias + relu + bf16 pack; lane holds 4 consecutive n for fixed m
#pragma unroll
    for (int ni = 0; ni < 2; ++ni) {
      int n0 = c * 128 + w * 32 + ni * 16 + lq * 4;
      float4 bv = *(const float4*)(b1 + n0);
#pragma unroll
      for (int mi = 0; mi < 4; ++mi) {
        f32x4 a = acc1[mi][ni];
        float x0 = fmaxf(a[0] + bv.x, 0.0f);
        float x1 = fmaxf(a[1] + bv.y, 0.0f);
        float x2 = fmaxf(a[2] + bv.z, 0.0f);
        float x3 = fmaxf(a[3] + bv.w, 0.0f);
        int m = mi * 16 + l15;
        int nl0 = w * 32 + ni * 16 + lq * 4;
        uint2 pk;
        pk.x = f2bf(x0) | ((unsigned)f2bf(x1) << 16);
        pk.y = f2bf(x2) | ((unsigned)f2bf(x3) << 16);
        *(uint2*)&Hs[m * 128 + (nl0 ^ ((m & 7) << 3))] = pk;
      }
    }
    BARRIER();
    // ---- GEMM2 partial: acc2 += W2[c*128:+128, :] (packed frags) @ h-slice ----
    const unsigned short* w2p = w2base + c * 2048;
#pragma unroll
    for (int kq = 0; kq < 4; ++kq) {
      bf16x8 vf[4];
#pragma unroll
      for (int nj = 0; nj < 4; ++nj)
        vf[nj] = *(const bf16x8*)(w2p + nj * 12288 + kq * 512);
      bf16x8 hf[4];
#pragma unroll
      for (int mi = 0; mi < 4; ++mi) {
        int row = mi * 16 + l15;
        int kidx = kq * 32 + lq * 8;
        hf[mi] = *(const bf16x8*)&Hs[row * 128 + (kidx ^ ((row & 7) << 3))];
      }
#pragma unroll
      for (int mi = 0; mi < 4; ++mi)
#pragma unroll
        for (int nj = 0; nj < 4; ++nj)
          acc2[mi][nj] = __builtin_amdgcn_mfma_f32_16x16x32_bf16(vf[nj], hf[mi], acc2[mi][nj], 0, 0, 0);
    }
  }

  // ---- epilogue: +b2, float4 stores (lane owns 4 consecutive nout) ----
#pragma unroll
  for (int nj = 0; nj < 4; ++nj) {
    int n0 = w * 64 + nj * 16 + lq * 4;
    float4 bv = *(const float4*)(b2 + n0);
#pragma unroll
    for (int mi = 0; mi < 4; ++mi) {
      int m = mi * 16 + l15;
      f32x4 a = acc2[mi][nj];
      float4 o;
      o.x = a[0] + bv.x; o.y = a[1] + bv.y; o.z = a[2] + bv.z; o.w = a[3] + bv.w;
      *(float4*)(out + ((size_t)bb * NR + r0 + m) * NH + n0) = o;
    }
  }
}

extern "C" void kernel_launch(void* const* d_in, const int* in_sizes, int n_in,
                              void* d_out, int out_size, void* d_ws, size_t ws_size,
                              hipStream_t stream) {
  const float* span = (const float*)d_in[0];
  const int* ids = (const int*)d_in[1];
  const float* W1 = (const float*)d_in[2];
  const float* b1 = (const float*)d_in[3];
  const float* W2 = (const float*)d_in[4];
  const float* b2 = (const float*)d_in[5];
  float* out = (float*)d_out;

  char* ws = (char*)d_ws;
  int* flag = (int*)ws;
  unsigned short* w1f = (unsigned short*)(ws + 64);                    // 49152*16B
  unsigned short* w2f = (unsigned short*)(ws + 64 + NF * NK * 2);      // 24576*16B

  detect_idw<<<1, 256, 0, stream>>>(ids, flag);
  prep_w1<<<192, 256, 0, stream>>>(W1, w1f);
  prep_w2<<<96, 256, 0, stream>>>(W2, w2f);
  fused_relffn<<<4096, 256, 0, stream>>>(span, ids, b1, b2, w1f, w2f, flag, out);
}

// Round 5
// 307.024 us; speedup vs baseline: 3.5162x; 1.1309x over previous
//
#include <hip/hip_runtime.h>

#define NB 4
#define NS 1024
#define NH 256
#define NR 65536
#define NF 768
#define NK 512

typedef __attribute__((ext_vector_type(8))) short bf16x8;
typedef __attribute__((ext_vector_type(4))) float f32x4;

static __device__ __forceinline__ unsigned short f2bf(float f) {
  unsigned int u = __builtin_bit_cast(unsigned int, f);
  u += 0x7FFFu + ((u >> 16) & 1u);   // RTNE
  return (unsigned short)(u >> 16);
}

// HW packed convert: lo = bf16(a), hi = bf16(b), RTNE.
static __device__ __forceinline__ unsigned cvt_pk(float a, float b) {
  unsigned r;
  asm("v_cvt_pk_bf16_f32 %0, %1, %2" : "=v"(r) : "v"(a), "v"(b));
  return r;
}

// Raw barrier: lgkmcnt(0) only -- does NOT drain vmcnt, so in-flight global
// loads survive the barrier.
#define BARRIER()                                            \
  do {                                                       \
    asm volatile("s_waitcnt lgkmcnt(0)" ::: "memory");       \
    __builtin_amdgcn_s_barrier();                            \
    asm volatile("" ::: "memory");                           \
  } while (0)

// Combined prep: blocks [0,192) pack W1, [192,288) pack W2, block 288 detects
// the rel_ids element width (int64 => odd int32 words all zero; ids < 1024).
__global__ void prep_all(const float* __restrict__ w1, const float* __restrict__ w2,
                         const int* __restrict__ ids,
                         unsigned short* __restrict__ w1f,
                         unsigned short* __restrict__ w2f,
                         int* __restrict__ flag) {
  int bid = blockIdx.x;
  if (bid < 192) {
    // W1 (512x768 f32) -> W1F fragment-packed bf16.
    // unit u = (((c*4 + w)*2 + half)*16 + kk)*64 + lane holds
    // W1col[row = c*128+w*32+half*16+(lane&15)][k = kk*32+(lane>>4)*8 +0..7]
    int t = bid * 256 + threadIdx.x;
    int l = t & 63;
    int kk = (t >> 6) & 15;
    int half = (t >> 10) & 1;
    int w = (t >> 11) & 3;
    int c = t >> 13;
    int row = c * 128 + w * 32 + half * 16 + (l & 15);
    int k0 = kk * 32 + (l >> 4) * 8;
    uint4 pk;
    unsigned short v[8];
#pragma unroll
    for (int j = 0; j < 8; ++j) v[j] = f2bf(w1[(size_t)(k0 + j) * NF + row]);
    pk.x = v[0] | ((unsigned)v[1] << 16);
    pk.y = v[2] | ((unsigned)v[3] << 16);
    pk.z = v[4] | ((unsigned)v[5] << 16);
    pk.w = v[6] | ((unsigned)v[7] << 16);
    *(uint4*)(w1f + (size_t)t * 8) = pk;
  } else if (bid < 288) {
    // W2 (768x256 f32) -> W2F fragment-packed bf16.
    // unit u = (((w*4 + nj)*6 + c)*4 + kq)*64 + lane holds
    // W2col[row = w*64+nj*16+(lane&15)][k = c*128+kq*32+(lane>>4)*8 +0..7]
    int t = (bid - 192) * 256 + threadIdx.x;
    int l = t & 63;
    int kq = (t >> 6) & 3;
    int rest = t >> 8;
    int c = rest % 6;
    int wn = rest / 6;
    int nj = wn & 3;
    int w = wn >> 2;
    int row = w * 64 + nj * 16 + (l & 15);
    int k = c * 128 + kq * 32 + (l >> 4) * 8;
    uint4 pk;
    unsigned short v[8];
#pragma unroll
    for (int j = 0; j < 8; ++j) v[j] = f2bf(w2[(size_t)(k + j) * NH + row]);
    pk.x = v[0] | ((unsigned)v[1] << 16);
    pk.y = v[2] | ((unsigned)v[3] << 16);
    pk.z = v[4] | ((unsigned)v[5] << 16);
    pk.w = v[6] | ((unsigned)v[7] << 16);
    *(uint4*)(w2f + (size_t)t * 8) = pk;
  } else {
    __shared__ int anynz;
    if (threadIdx.x == 0) anynz = 0;
    __syncthreads();
    int acc = 0;
    for (int i = threadIdx.x; i < 8192; i += 256) acc |= ids[2 * i + 1];
    if (acc != 0) atomicOr(&anynz, 1);
    __syncthreads();
    if (threadIdx.x == 0) flag[0] = (anynz == 0) ? 1 : 0;  // 1 => int64
  }
}

// Fused: gather -> GEMM1(relu,+b1) -> GEMM2(+b2), 64 rows per block, 4 waves.
// Chunk-PAIR structure: one kk-sweep over As feeds two 128-col chunks (af
// fragments reused 2x -> As LDS reads halve). af double-buffered; wf 2-deep.
__global__ __launch_bounds__(256, 2)
void fused_relffn(const float* __restrict__ span, const int* __restrict__ ids,
                  const float* __restrict__ b1, const float* __restrict__ b2,
                  const unsigned short* __restrict__ w1f,
                  const unsigned short* __restrict__ w2f,
                  const int* __restrict__ flagp, float* __restrict__ out) {
  __shared__ __align__(16) unsigned short As[64 * 512];  // 64 KB, swizzled
  __shared__ __align__(16) unsigned short Hs[64 * 128];  // 16 KB, swizzled

  const int tid = threadIdx.x;
  const int blk = blockIdx.x;
  const int bb = blk >> 10;              // batch
  const int r0 = (blk & 1023) << 6;      // first relation row
  const int lane = tid & 63;
  const int w = tid >> 6;                // wave 0..3
  const int l15 = lane & 15;
  const int lq = lane >> 4;              // 0..3
  const int is64 = flagp[0];

  // Packed W1 base: + c*65536 per chunk, + 8192 for half=1, + kk*512.
  const unsigned short* w1base = w1f + w * 16384 + lane * 8;
  // Packed W2 base: + nj*12288 + c*2048 + kq*512.
  const unsigned short* w2base = w2f + w * 49152 + lane * 8;

  // ---- gather A tile: ids preloaded, then unrolled load/convert ----
  {
    const long pair0 = ((long)bb * NR + r0) * 2;
    int idv[16];
#pragma unroll
    for (int j = 0; j < 16; ++j) {
      int g = tid + j * 256;
      int row = g >> 6;
      int kc = g & 63;
      long pidx = pair0 + row * 2 + (kc >> 5);
      idv[j] = is64 ? ids[pidx * 2] : ids[pidx];
    }
#pragma unroll
    for (int j = 0; j < 16; ++j) {
      int g = tid + j * 256;
      int row = g >> 6;
      int kc = g & 63;
      const float* src = span + ((size_t)bb * NS + idv[j]) * NH + (kc & 31) * 8;
      float4 v0 = *(const float4*)src;
      float4 v1 = *(const float4*)(src + 4);
      uint4 pk;
      pk.x = cvt_pk(v0.x, v0.y);
      pk.y = cvt_pk(v0.z, v0.w);
      pk.z = cvt_pk(v1.x, v1.y);
      pk.w = cvt_pk(v1.z, v1.w);
      int idx = row * 512 + ((kc * 8) ^ ((row & 7) << 3));  // XOR swizzle
      *(uint4*)&As[idx] = pk;
    }
  }
  BARRIER();

  f32x4 acc2[4][4];
#pragma unroll
  for (int mi = 0; mi < 4; ++mi)
#pragma unroll
    for (int nj = 0; nj < 4; ++nj) {
      f32x4 z = {0.f, 0.f, 0.f, 0.f};
      acc2[mi][nj] = z;
    }

  for (int cp = 0; cp < 3; ++cp) {
    const int ca = cp * 2, cb = ca + 1;
    const unsigned short* wpa = w1base + ca * 65536;
    const unsigned short* wpb = w1base + cb * 65536;

    // ---- GEMM1 pair: one af sweep feeds chunks ca and cb ----
    f32x4 acc1a[4][2], acc1b[4][2];
#pragma unroll
    for (int mi = 0; mi < 4; ++mi)
#pragma unroll
      for (int ni = 0; ni < 2; ++ni) {
        f32x4 z = {0.f, 0.f, 0.f, 0.f};
        acc1a[mi][ni] = z;
        acc1b[mi][ni] = z;
      }

    bf16x8 wfa[2][2], wfb[2][2];   // [depth][half]
#pragma unroll
    for (int d = 0; d < 2; ++d) {
      wfa[d][0] = *(const bf16x8*)(wpa + d * 512);
      wfa[d][1] = *(const bf16x8*)(wpa + 8192 + d * 512);
      wfb[d][0] = *(const bf16x8*)(wpb + d * 512);
      wfb[d][1] = *(const bf16x8*)(wpb + 8192 + d * 512);
    }
    bf16x8 afp[2][4];              // af double buffer
#pragma unroll
    for (int mi = 0; mi < 4; ++mi) {
      int row = mi * 16 + l15;
      afp[0][mi] = *(const bf16x8*)&As[row * 512 + ((lq * 8) ^ ((row & 7) << 3))];
    }

#pragma unroll
    for (int kk = 0; kk < 16; ++kk) {
      const int cur = kk & 1;
      if (kk < 15) {   // prefetch next kk's af
#pragma unroll
        for (int mi = 0; mi < 4; ++mi) {
          int row = mi * 16 + l15;
          int kidx = (kk + 1) * 32 + lq * 8;
          afp[cur ^ 1][mi] = *(const bf16x8*)&As[row * 512 + (kidx ^ ((row & 7) << 3))];
        }
      }
      bf16x8 ca0 = wfa[cur][0], ca1 = wfa[cur][1];
      bf16x8 cb0 = wfb[cur][0], cb1 = wfb[cur][1];
      if (kk < 14) {   // refill wf slot with kk+2
        wfa[cur][0] = *(const bf16x8*)(wpa + (kk + 2) * 512);
        wfa[cur][1] = *(const bf16x8*)(wpa + 8192 + (kk + 2) * 512);
        wfb[cur][0] = *(const bf16x8*)(wpb + (kk + 2) * 512);
        wfb[cur][1] = *(const bf16x8*)(wpb + 8192 + (kk + 2) * 512);
      }
      __builtin_amdgcn_s_setprio(1);
#pragma unroll
      for (int mi = 0; mi < 4; ++mi) {
        bf16x8 a = afp[cur][mi];
        acc1a[mi][0] = __builtin_amdgcn_mfma_f32_16x16x32_bf16(ca0, a, acc1a[mi][0], 0, 0, 0);
        acc1a[mi][1] = __builtin_amdgcn_mfma_f32_16x16x32_bf16(ca1, a, acc1a[mi][1], 0, 0, 0);
        acc1b[mi][0] = __builtin_amdgcn_mfma_f32_16x16x32_bf16(cb0, a, acc1b[mi][0], 0, 0, 0);
        acc1b[mi][1] = __builtin_amdgcn_mfma_f32_16x16x32_bf16(cb1, a, acc1b[mi][1], 0, 0, 0);
      }
      __builtin_amdgcn_s_setprio(0);
    }

    // ---- chunk ca: pack -> GEMM2; then chunk cb ----
#pragma unroll
    for (int half = 0; half < 2; ++half) {
      const int c = half ? cb : ca;
      BARRIER();   // prior GEMM2's Hs reads done before overwrite
#pragma unroll
      for (int ni = 0; ni < 2; ++ni) {
        int n0 = c * 128 + w * 32 + ni * 16 + lq * 4;
        float4 bv = *(const float4*)(b1 + n0);
#pragma unroll
        for (int mi = 0; mi < 4; ++mi) {
          f32x4 a = half ? acc1b[mi][ni] : acc1a[mi][ni];
          float x0 = fmaxf(a[0] + bv.x, 0.0f);
          float x1 = fmaxf(a[1] + bv.y, 0.0f);
          float x2 = fmaxf(a[2] + bv.z, 0.0f);
          float x3 = fmaxf(a[3] + bv.w, 0.0f);
          int m = mi * 16 + l15;
          int nl0 = w * 32 + ni * 16 + lq * 4;
          uint2 pk;
          pk.x = cvt_pk(x0, x1);
          pk.y = cvt_pk(x2, x3);
          *(uint2*)&Hs[m * 128 + (nl0 ^ ((m & 7) << 3))] = pk;
        }
      }
      BARRIER();
      const unsigned short* w2p = w2base + c * 2048;
#pragma unroll
      for (int kq = 0; kq < 4; ++kq) {
        bf16x8 vf[4];
#pragma unroll
        for (int nj = 0; nj < 4; ++nj)
          vf[nj] = *(const bf16x8*)(w2p + nj * 12288 + kq * 512);
        bf16x8 hf[4];
#pragma unroll
        for (int mi = 0; mi < 4; ++mi) {
          int row = mi * 16 + l15;
          int kidx = kq * 32 + lq * 8;
          hf[mi] = *(const bf16x8*)&Hs[row * 128 + (kidx ^ ((row & 7) << 3))];
        }
        __builtin_amdgcn_s_setprio(1);
#pragma unroll
        for (int mi = 0; mi < 4; ++mi)
#pragma unroll
          for (int nj = 0; nj < 4; ++nj)
            acc2[mi][nj] = __builtin_amdgcn_mfma_f32_16x16x32_bf16(vf[nj], hf[mi], acc2[mi][nj], 0, 0, 0);
        __builtin_amdgcn_s_setprio(0);
      }
    }
  }

  // ---- epilogue: +b2, float4 stores (lane owns 4 consecutive nout) ----
#pragma unroll
  for (int nj = 0; nj < 4; ++nj) {
    int n0 = w * 64 + nj * 16 + lq * 4;
    float4 bv = *(const float4*)(b2 + n0);
#pragma unroll
    for (int mi = 0; mi < 4; ++mi) {
      int m = mi * 16 + l15;
      f32x4 a = acc2[mi][nj];
      float4 o;
      o.x = a[0] + bv.x; o.y = a[1] + bv.y; o.z = a[2] + bv.z; o.w = a[3] + bv.w;
      *(float4*)(out + ((size_t)bb * NR + r0 + m) * NH + n0) = o;
    }
  }
}

extern "C" void kernel_launch(void* const* d_in, const int* in_sizes, int n_in,
                              void* d_out, int out_size, void* d_ws, size_t ws_size,
                              hipStream_t stream) {
  const float* span = (const float*)d_in[0];
  const int* ids = (const int*)d_in[1];
  const float* W1 = (const float*)d_in[2];
  const float* b1 = (const float*)d_in[3];
  const float* W2 = (const float*)d_in[4];
  const float* b2 = (const float*)d_in[5];
  float* out = (float*)d_out;

  char* ws = (char*)d_ws;
  int* flag = (int*)ws;
  unsigned short* w1f = (unsigned short*)(ws + 64);                    // 49152*16B
  unsigned short* w2f = (unsigned short*)(ws + 64 + NF * NK * 2);      // 24576*16B

  prep_all<<<289, 256, 0, stream>>>(W1, W2, ids, w1f, w2f, flag);
  fused_relffn<<<4096, 256, 0, stream>>>(span, ids, b1, b2, w1f, w2f, flag, out);
}